// Round 1
// baseline (762.350 us; speedup 1.0000x reference)
//
#include <hip/hip_runtime.h>

#define DEV_INLINE __device__ __forceinline__

// Dense layer: input activations in LDS (per-thread region, dynamic k index),
// accumulators in registers (constant-indexed), weights via wave-uniform
// float4 loads (scalarizable to s_load + SGPR-operand FMA).
template<int K, int JOUT>
DEV_INLINE void dense_lds(const float* h_in, const float* __restrict__ W,
                          const float* __restrict__ Bb, int jbase, int ldw,
                          float* acc)
{
#pragma unroll
    for (int j4 = 0; j4 < JOUT / 4; ++j4) {
        float4 bb = *(const float4*)&Bb[jbase + j4 * 4];
        acc[j4 * 4 + 0] = bb.x; acc[j4 * 4 + 1] = bb.y;
        acc[j4 * 4 + 2] = bb.z; acc[j4 * 4 + 3] = bb.w;
    }
    for (int k = 0; k < K; ++k) {          // rolled: uniform k, weights uniform
        float a = h_in[k];
#pragma unroll
        for (int j4 = 0; j4 < JOUT / 4; ++j4) {
            float4 w = *(const float4*)&W[k * ldw + jbase + j4 * 4];
            acc[j4 * 4 + 0] = fmaf(a, w.x, acc[j4 * 4 + 0]);
            acc[j4 * 4 + 1] = fmaf(a, w.y, acc[j4 * 4 + 1]);
            acc[j4 * 4 + 2] = fmaf(a, w.z, acc[j4 * 4 + 2]);
            acc[j4 * 4 + 3] = fmaf(a, w.w, acc[j4 * 4 + 3]);
        }
    }
}

// ---------------- Set encoder: [B, 64*NELEM, DIN] -> [B, 32] ----------------
// Block = 256 threads = 4 waves; each wave owns one batch row; lane owns
// NELEM set elements. Pool (mean+max)/2 across the set via LDS transpose.
template<int DIN, int NELEM>
__global__ __launch_bounds__(256)
void set_enc_kernel(const float* __restrict__ X,
                    const float* __restrict__ w1, const float* __restrict__ b1,
                    const float* __restrict__ w2, const float* __restrict__ b2,
                    const float* __restrict__ w3, const float* __restrict__ b3,
                    float* __restrict__ out)
{
    __shared__ float ht[256 * 65];          // 65-stride pad: conflict-free
    const int tid  = threadIdx.x;
    const int wave = tid >> 6;
    const int lane = tid & 63;
    const int b    = blockIdx.x * 4 + wave;
    float* myh = &ht[tid * 65];

    float ps[32], pm[32];

#pragma unroll
    for (int e = 0; e < NELEM; ++e) {
        const int n = lane + e * 64;
        const float* xp = X + ((size_t)b * (64 * NELEM) + n) * DIN;
        float x[DIN];
#pragma unroll
        for (int k = 0; k < DIN; ++k) x[k] = xp[k];

        // L1: DIN -> 64, relu  (x in regs, fully unrolled)
        float acc[64];
#pragma unroll
        for (int j4 = 0; j4 < 16; ++j4) {
            float4 bb = *(const float4*)&b1[j4 * 4];
            acc[j4 * 4 + 0] = bb.x; acc[j4 * 4 + 1] = bb.y;
            acc[j4 * 4 + 2] = bb.z; acc[j4 * 4 + 3] = bb.w;
        }
#pragma unroll
        for (int k = 0; k < DIN; ++k) {
#pragma unroll
            for (int j4 = 0; j4 < 16; ++j4) {
                float4 w = *(const float4*)&w1[k * 64 + j4 * 4];
                acc[j4 * 4 + 0] = fmaf(x[k], w.x, acc[j4 * 4 + 0]);
                acc[j4 * 4 + 1] = fmaf(x[k], w.y, acc[j4 * 4 + 1]);
                acc[j4 * 4 + 2] = fmaf(x[k], w.z, acc[j4 * 4 + 2]);
                acc[j4 * 4 + 3] = fmaf(x[k], w.w, acc[j4 * 4 + 3]);
            }
        }
#pragma unroll
        for (int j = 0; j < 64; ++j) myh[j] = fmaxf(acc[j], 0.0f);

        // L2: 64 -> 64, relu
        dense_lds<64, 64>(myh, w2, b2, 0, 64, acc);
#pragma unroll
        for (int j = 0; j < 64; ++j) myh[j] = fmaxf(acc[j], 0.0f);

        // L3: 64 -> 32 (linear)
        float e3[32];
        dense_lds<64, 32>(myh, w3, b3, 0, 32, e3);

        if (e == 0) {
#pragma unroll
            for (int j = 0; j < 32; ++j) { ps[j] = e3[j]; pm[j] = e3[j]; }
        } else {
#pragma unroll
            for (int j = 0; j < 32; ++j) { ps[j] += e3[j]; pm[j] = fmaxf(pm[j], e3[j]); }
        }
    }

    // stash per-lane partials for cross-lane pooling
#pragma unroll
    for (int j = 0; j < 32; ++j) { myh[j] = ps[j]; myh[32 + j] = pm[j]; }
    __syncthreads();

    if (lane < 32) {
        const int o = lane;
        float s = 0.0f, m = -3.4e38f;
        for (int t = 0; t < 64; ++t) {
            const float* rowp = &ht[(wave * 64 + t) * 65];
            s += rowp[o];
            m = fmaxf(m, rowp[32 + o]);
        }
        out[(size_t)b * 32 + o] = 0.5f * (s * (1.0f / (64.0f * NELEM)) + m);
    }
}

// ---------------- Head MLP: concat[108] -> 128 -> 128 -> 64 -> 1 ------------
// Block = 256 = 4 waves. 64 rows/block; wave p owns output-slice p for all
// 64 rows (lane = row), so weight addresses stay wave-uniform.
__global__ __launch_bounds__(256)
void head_kernel(const float* __restrict__ t0,
                 const float* __restrict__ remb, const float* __restrict__ temb,
                 const float* __restrict__ w1, const float* __restrict__ b1,
                 const float* __restrict__ w2, const float* __restrict__ b2,
                 const float* __restrict__ w3, const float* __restrict__ b3,
                 const float* __restrict__ w4, const float* __restrict__ b4,
                 float* __restrict__ out)
{
    __shared__ float cbuf[64 * 109];
    __shared__ float hbuf[64 * 129];
    __shared__ float pbuf[64 * 5];
    const int tid = threadIdx.x;
    const int p   = tid >> 6;      // wave id = output-slice id
    const int r   = tid & 63;      // row within block
    const int g0  = blockIdx.x * 64;
    const int g   = g0 + r;

    // stage concat input c[108] = [tier0(44) | remb(32) | temb(32)]
    for (int i = tid; i < 64 * 44; i += 256) {
        int rr = i / 44, k = i - rr * 44;
        cbuf[rr * 109 + k] = t0[(size_t)(g0 + rr) * 44 + k];
    }
    for (int i = tid; i < 64 * 32; i += 256) {
        int rr = i >> 5, k = i & 31;
        cbuf[rr * 109 + 44 + k] = remb[(size_t)(g0 + rr) * 32 + k];
    }
    for (int i = tid; i < 64 * 32; i += 256) {
        int rr = i >> 5, k = i & 31;
        cbuf[rr * 109 + 76 + k] = temb[(size_t)(g0 + rr) * 32 + k];
    }
    __syncthreads();

    const float* myc = &cbuf[r * 109];
    float* myh = &hbuf[r * 129];

    // L1: 108 -> 128, thread owns outputs [p*32, p*32+32)
    {
        float acc[32];
        dense_lds<108, 32>(myc, w1, b1, p * 32, 128, acc);
#pragma unroll
        for (int j = 0; j < 32; ++j) myh[p * 32 + j] = fmaxf(acc[j], 0.0f);
    }
    __syncthreads();

    // L2: 128 -> 128
    {
        float acc[32];
        dense_lds<128, 32>(myh, w2, b2, p * 32, 128, acc);
        __syncthreads();                       // all reads of h1 done
#pragma unroll
        for (int j = 0; j < 32; ++j) myh[p * 32 + j] = fmaxf(acc[j], 0.0f);
    }
    __syncthreads();

    // L3: 128 -> 64, thread owns outputs [p*16, p*16+16)
    {
        float acc[16];
        dense_lds<128, 16>(myh, w3, b3, p * 16, 64, acc);
        __syncthreads();
#pragma unroll
        for (int j = 0; j < 16; ++j) myh[p * 16 + j] = fmaxf(acc[j], 0.0f);
    }
    __syncthreads();

    // L4: 64 -> 1 (split dot across the 4 waves)
    {
        float part = 0.0f;
#pragma unroll
        for (int u = 0; u < 16; ++u)
            part = fmaf(myh[p * 16 + u], w4[p * 16 + u], part);
        pbuf[r * 5 + p] = part;
    }
    __syncthreads();
    if (p == 0)
        out[g] = pbuf[r * 5 + 0] + pbuf[r * 5 + 1] + pbuf[r * 5 + 2] +
                 pbuf[r * 5 + 3] + b4[0];
}

extern "C" void kernel_launch(void* const* d_in, const int* in_sizes, int n_in,
                              void* d_out, int out_size, void* d_ws, size_t ws_size,
                              hipStream_t stream)
{
    const float* t0  = (const float*)d_in[0];
    const float* rX  = (const float*)d_in[1];
    const float* tX  = (const float*)d_in[2];
    const float* rw1 = (const float*)d_in[3];  const float* rb1 = (const float*)d_in[4];
    const float* rw2 = (const float*)d_in[5];  const float* rb2 = (const float*)d_in[6];
    const float* rw3 = (const float*)d_in[7];  const float* rb3 = (const float*)d_in[8];
    const float* tw1 = (const float*)d_in[9];  const float* tb1 = (const float*)d_in[10];
    const float* tw2 = (const float*)d_in[11]; const float* tb2 = (const float*)d_in[12];
    const float* tw3 = (const float*)d_in[13]; const float* tb3 = (const float*)d_in[14];
    const float* mw1 = (const float*)d_in[15]; const float* mb1 = (const float*)d_in[16];
    const float* mw2 = (const float*)d_in[17]; const float* mb2 = (const float*)d_in[18];
    const float* mw3 = (const float*)d_in[19]; const float* mb3 = (const float*)d_in[20];
    const float* mw4 = (const float*)d_in[21]; const float* mb4 = (const float*)d_in[22];
    float* out = (float*)d_out;

    const int B = 16384;
    float* remb = (float*)d_ws;                 // [B,32]
    float* temb = remb + (size_t)B * 32;        // [B,32]

    set_enc_kernel<6, 1><<<B / 4, 256, 0, stream>>>(rX, rw1, rb1, rw2, rb2, rw3, rb3, remb);
    set_enc_kernel<7, 2><<<B / 4, 256, 0, stream>>>(tX, tw1, tb1, tw2, tb2, tw3, tb3, temb);
    head_kernel<<<B / 64, 256, 0, stream>>>(t0, remb, temb,
                                            mw1, mb1, mw2, mb2, mw3, mb3, mw4, mb4, out);
}

// Round 2
// 485.111 us; speedup vs baseline: 1.5715x; 1.5715x over previous
//
#include <hip/hip_runtime.h>

#define DEV_INLINE __device__ __forceinline__

typedef __bf16 bf16x8 __attribute__((ext_vector_type(8)));
typedef float  floatx4 __attribute__((ext_vector_type(4)));

DEV_INLINE bf16x8 ld_frag(const __bf16* p) {
    union { uint4 u; bf16x8 v; } t;
    t.u = *(const uint4*)p;
    return t.v;
}

// ---------------------------------------------------------------------------
// MFMA set encoder: rows = B*S element-rows of [DIN] -> 64 -> 64 -> 32,
// then (mean+max)/2 pooling over each S-row group.
// Block = 256 threads (4 waves), processes R=128 element-rows.
// L1 in fp32 VALU (K tiny, keeps input precision); L2/L3 bf16 MFMA.
// LDS layout: h1/h2 bf16 stride 72 (16B-aligned frags, conflict-padded);
// e3 fp32 stride 34 aliases h1 after L2 is done.
// ---------------------------------------------------------------------------
template<int DIN, int S>
__global__ __launch_bounds__(256)
void enc_mfma(const float* __restrict__ X,
              const float* __restrict__ w1, const float* __restrict__ b1,
              const float* __restrict__ w2, const float* __restrict__ b2,
              const float* __restrict__ w3, const float* __restrict__ b3,
              float* __restrict__ out)
{
    constexpr int NB = 128 / S;          // batches per block (1 or 2)
    __shared__ __align__(16) __bf16 h1[128 * 72];
    __shared__ __align__(16) __bf16 h2[128 * 72];
    __shared__ __align__(16) __bf16 wt2[64 * 72];   // w2^T: [n][k]
    __shared__ __align__(16) __bf16 wt3[32 * 72];   // w3^T: [n][k]
    __shared__ float pool[512];
    float* e3 = (float*)h1;              // [128][34], valid after phase-2 barrier

    const int tid = threadIdx.x;
    const int w   = tid >> 6;            // wave id: owns row-tiles {2w, 2w+1}
    const int l64 = tid & 63;
    const int ln  = l64 & 15;            // MFMA lane-in-16
    const int qd  = l64 >> 4;            // MFMA quad

    // ---- phase 0: stage weights (bf16, transposed) + L1 fp32 ----
    for (int i = tid; i < 64 * 64; i += 256) {
        int k = i >> 6, n = i & 63;
        wt2[n * 72 + k] = (__bf16)w2[i];
    }
    for (int i = tid; i < 64 * 32; i += 256) {
        int k = i >> 5, n = i & 31;
        wt3[n * 72 + k] = (__bf16)w3[i];
    }
    {
        const int r  = tid & 127;
        const int j0 = (tid >> 7) * 32;  // two threads per row, 32 outs each
        const float* xp = X + ((size_t)blockIdx.x * 128 + r) * DIN;
        float x[DIN];
#pragma unroll
        for (int k = 0; k < DIN; ++k) x[k] = xp[k];
        float acc[32];
#pragma unroll
        for (int j4 = 0; j4 < 8; ++j4) {
            float4 bb = *(const float4*)&b1[j0 + j4 * 4];
            acc[j4 * 4 + 0] = bb.x; acc[j4 * 4 + 1] = bb.y;
            acc[j4 * 4 + 2] = bb.z; acc[j4 * 4 + 3] = bb.w;
        }
#pragma unroll
        for (int k = 0; k < DIN; ++k) {
#pragma unroll
            for (int j4 = 0; j4 < 8; ++j4) {
                float4 wv = *(const float4*)&w1[k * 64 + j0 + j4 * 4];
                acc[j4 * 4 + 0] = fmaf(x[k], wv.x, acc[j4 * 4 + 0]);
                acc[j4 * 4 + 1] = fmaf(x[k], wv.y, acc[j4 * 4 + 1]);
                acc[j4 * 4 + 2] = fmaf(x[k], wv.z, acc[j4 * 4 + 2]);
                acc[j4 * 4 + 3] = fmaf(x[k], wv.w, acc[j4 * 4 + 3]);
            }
        }
#pragma unroll
        for (int c = 0; c < 4; ++c) {
            union { __bf16 h[8]; uint4 u; } pk;
#pragma unroll
            for (int u = 0; u < 8; ++u)
                pk.h[u] = (__bf16)fmaxf(acc[c * 8 + u], 0.0f);
            *(uint4*)&h1[r * 72 + j0 + c * 8] = pk.u;
        }
    }
    __syncthreads();

    // ---- phase 2: L2 = relu(h1 @ w2 + b2), 128x64 @ 64x64, MFMA ----
    {
        floatx4 acc[2][4];
#pragma unroll
        for (int nt = 0; nt < 4; ++nt) {
            float bv = b2[nt * 16 + ln];
            acc[0][nt] = (floatx4){bv, bv, bv, bv};
            acc[1][nt] = (floatx4){bv, bv, bv, bv};
        }
#pragma unroll
        for (int kq = 0; kq < 2; ++kq) {
            bf16x8 a0 = ld_frag(&h1[((2 * w + 0) * 16 + ln) * 72 + kq * 32 + qd * 8]);
            bf16x8 a1 = ld_frag(&h1[((2 * w + 1) * 16 + ln) * 72 + kq * 32 + qd * 8]);
#pragma unroll
            for (int nt = 0; nt < 4; ++nt) {
                bf16x8 bfr = ld_frag(&wt2[(nt * 16 + ln) * 72 + kq * 32 + qd * 8]);
                acc[0][nt] = __builtin_amdgcn_mfma_f32_16x16x32_bf16(a0, bfr, acc[0][nt], 0, 0, 0);
                acc[1][nt] = __builtin_amdgcn_mfma_f32_16x16x32_bf16(a1, bfr, acc[1][nt], 0, 0, 0);
            }
        }
#pragma unroll
        for (int i = 0; i < 2; ++i)
#pragma unroll
            for (int nt = 0; nt < 4; ++nt)
#pragma unroll
                for (int rg = 0; rg < 4; ++rg)
                    h2[((2 * w + i) * 16 + qd * 4 + rg) * 72 + nt * 16 + ln] =
                        (__bf16)fmaxf(acc[i][nt][rg], 0.0f);
    }
    __syncthreads();   // h1 free; e3 aliases it below

    // ---- phase 3: L3 = h2 @ w3 + b3, 128x64 @ 64x32, MFMA, fp32 out ----
    {
        floatx4 acc[2][2];
#pragma unroll
        for (int nt = 0; nt < 2; ++nt) {
            float bv = b3[nt * 16 + ln];
            acc[0][nt] = (floatx4){bv, bv, bv, bv};
            acc[1][nt] = (floatx4){bv, bv, bv, bv};
        }
#pragma unroll
        for (int kq = 0; kq < 2; ++kq) {
            bf16x8 a0 = ld_frag(&h2[((2 * w + 0) * 16 + ln) * 72 + kq * 32 + qd * 8]);
            bf16x8 a1 = ld_frag(&h2[((2 * w + 1) * 16 + ln) * 72 + kq * 32 + qd * 8]);
#pragma unroll
            for (int nt = 0; nt < 2; ++nt) {
                bf16x8 bfr = ld_frag(&wt3[(nt * 16 + ln) * 72 + kq * 32 + qd * 8]);
                acc[0][nt] = __builtin_amdgcn_mfma_f32_16x16x32_bf16(a0, bfr, acc[0][nt], 0, 0, 0);
                acc[1][nt] = __builtin_amdgcn_mfma_f32_16x16x32_bf16(a1, bfr, acc[1][nt], 0, 0, 0);
            }
        }
#pragma unroll
        for (int i = 0; i < 2; ++i)
#pragma unroll
            for (int nt = 0; nt < 2; ++nt)
#pragma unroll
                for (int rg = 0; rg < 4; ++rg)
                    e3[((2 * w + i) * 16 + qd * 4 + rg) * 34 + nt * 16 + ln] =
                        acc[i][nt][rg];
    }
    __syncthreads();

    // ---- phase 4: pooling (mean+max)/2 over S rows per batch ----
    {
        const int o  = tid & 31;
        const int bi = (tid >> 5) % NB;
        const int ch = tid / (32 * NB);           // C = 8/NB chunks of 16 rows
        float s = 0.0f, m = -3.4e38f;
#pragma unroll
        for (int r16 = 0; r16 < 16; ++r16) {
            float v = e3[(bi * S + ch * 16 + r16) * 34 + o];
            s += v;
            m = fmaxf(m, v);
        }
        pool[tid] = s;
        pool[256 + tid] = m;
    }
    __syncthreads();
    if (tid < NB * 32) {
        constexpr int C = 8 / NB;
        float s = 0.0f, m = -3.4e38f;
#pragma unroll
        for (int c = 0; c < C; ++c) {
            s += pool[tid + c * 32 * NB];
            m = fmaxf(m, pool[256 + tid + c * 32 * NB]);
        }
        size_t b = (size_t)blockIdx.x * NB + (tid >> 5);
        out[b * 32 + (tid & 31)] = 0.5f * (s * (1.0f / S) + m);
    }
}

// ---------------------------------------------------------------------------
// fp32 head (unchanged from R1): concat[108] -> 128 -> 128 -> 64 -> 1
// ---------------------------------------------------------------------------
template<int K, int JOUT>
DEV_INLINE void dense_lds(const float* h_in, const float* __restrict__ W,
                          const float* __restrict__ Bb, int jbase, int ldw,
                          float* acc)
{
#pragma unroll
    for (int j4 = 0; j4 < JOUT / 4; ++j4) {
        float4 bb = *(const float4*)&Bb[jbase + j4 * 4];
        acc[j4 * 4 + 0] = bb.x; acc[j4 * 4 + 1] = bb.y;
        acc[j4 * 4 + 2] = bb.z; acc[j4 * 4 + 3] = bb.w;
    }
    for (int k = 0; k < K; ++k) {
        float a = h_in[k];
#pragma unroll
        for (int j4 = 0; j4 < JOUT / 4; ++j4) {
            float4 w = *(const float4*)&W[k * ldw + jbase + j4 * 4];
            acc[j4 * 4 + 0] = fmaf(a, w.x, acc[j4 * 4 + 0]);
            acc[j4 * 4 + 1] = fmaf(a, w.y, acc[j4 * 4 + 1]);
            acc[j4 * 4 + 2] = fmaf(a, w.z, acc[j4 * 4 + 2]);
            acc[j4 * 4 + 3] = fmaf(a, w.w, acc[j4 * 4 + 3]);
        }
    }
}

__global__ __launch_bounds__(256)
void head_kernel(const float* __restrict__ t0,
                 const float* __restrict__ remb, const float* __restrict__ temb,
                 const float* __restrict__ w1, const float* __restrict__ b1,
                 const float* __restrict__ w2, const float* __restrict__ b2,
                 const float* __restrict__ w3, const float* __restrict__ b3,
                 const float* __restrict__ w4, const float* __restrict__ b4,
                 float* __restrict__ out)
{
    __shared__ float cbuf[64 * 109];
    __shared__ float hbuf[64 * 129];
    __shared__ float pbuf[64 * 5];
    const int tid = threadIdx.x;
    const int p   = tid >> 6;
    const int r   = tid & 63;
    const int g0  = blockIdx.x * 64;
    const int g   = g0 + r;

    for (int i = tid; i < 64 * 44; i += 256) {
        int rr = i / 44, k = i - rr * 44;
        cbuf[rr * 109 + k] = t0[(size_t)(g0 + rr) * 44 + k];
    }
    for (int i = tid; i < 64 * 32; i += 256) {
        int rr = i >> 5, k = i & 31;
        cbuf[rr * 109 + 44 + k] = remb[(size_t)(g0 + rr) * 32 + k];
    }
    for (int i = tid; i < 64 * 32; i += 256) {
        int rr = i >> 5, k = i & 31;
        cbuf[rr * 109 + 76 + k] = temb[(size_t)(g0 + rr) * 32 + k];
    }
    __syncthreads();

    const float* myc = &cbuf[r * 109];
    float* myh = &hbuf[r * 129];

    {
        float acc[32];
        dense_lds<108, 32>(myc, w1, b1, p * 32, 128, acc);
#pragma unroll
        for (int j = 0; j < 32; ++j) myh[p * 32 + j] = fmaxf(acc[j], 0.0f);
    }
    __syncthreads();
    {
        float acc[32];
        dense_lds<128, 32>(myh, w2, b2, p * 32, 128, acc);
        __syncthreads();
#pragma unroll
        for (int j = 0; j < 32; ++j) myh[p * 32 + j] = fmaxf(acc[j], 0.0f);
    }
    __syncthreads();
    {
        float acc[16];
        dense_lds<128, 16>(myh, w3, b3, p * 16, 64, acc);
        __syncthreads();
#pragma unroll
        for (int j = 0; j < 16; ++j) myh[p * 16 + j] = fmaxf(acc[j], 0.0f);
    }
    __syncthreads();
    {
        float part = 0.0f;
#pragma unroll
        for (int u = 0; u < 16; ++u)
            part = fmaf(myh[p * 16 + u], w4[p * 16 + u], part);
        pbuf[r * 5 + p] = part;
    }
    __syncthreads();
    if (p == 0)
        out[g] = pbuf[r * 5 + 0] + pbuf[r * 5 + 1] + pbuf[r * 5 + 2] +
                 pbuf[r * 5 + 3] + b4[0];
}

extern "C" void kernel_launch(void* const* d_in, const int* in_sizes, int n_in,
                              void* d_out, int out_size, void* d_ws, size_t ws_size,
                              hipStream_t stream)
{
    const float* t0  = (const float*)d_in[0];
    const float* rX  = (const float*)d_in[1];
    const float* tX  = (const float*)d_in[2];
    const float* rw1 = (const float*)d_in[3];  const float* rb1 = (const float*)d_in[4];
    const float* rw2 = (const float*)d_in[5];  const float* rb2 = (const float*)d_in[6];
    const float* rw3 = (const float*)d_in[7];  const float* rb3 = (const float*)d_in[8];
    const float* tw1 = (const float*)d_in[9];  const float* tb1 = (const float*)d_in[10];
    const float* tw2 = (const float*)d_in[11]; const float* tb2 = (const float*)d_in[12];
    const float* tw3 = (const float*)d_in[13]; const float* tb3 = (const float*)d_in[14];
    const float* mw1 = (const float*)d_in[15]; const float* mb1 = (const float*)d_in[16];
    const float* mw2 = (const float*)d_in[17]; const float* mb2 = (const float*)d_in[18];
    const float* mw3 = (const float*)d_in[19]; const float* mb3 = (const float*)d_in[20];
    const float* mw4 = (const float*)d_in[21]; const float* mb4 = (const float*)d_in[22];
    float* out = (float*)d_out;

    const int B = 16384;
    float* remb = (float*)d_ws;                 // [B,32]
    float* temb = remb + (size_t)B * 32;        // [B,32]

    enc_mfma<6, 64> <<<(B * 64) / 128, 256, 0, stream>>>(rX, rw1, rb1, rw2, rb2, rw3, rb3, remb);
    enc_mfma<7, 128><<<(B * 128) / 128, 256, 0, stream>>>(tX, tw1, tb1, tw2, tb2, tw3, tb3, temb);
    head_kernel<<<B / 64, 256, 0, stream>>>(t0, remb, temb,
                                            mw1, mb1, mw2, mb2, mw3, mb3, mw4, mb4, out);
}

// Round 3
// 337.246 us; speedup vs baseline: 2.2605x; 1.4385x over previous
//
#include <hip/hip_runtime.h>

#define DEV_INLINE __device__ __forceinline__

typedef __bf16 bf16x8 __attribute__((ext_vector_type(8)));
typedef float  floatx4 __attribute__((ext_vector_type(4)));

DEV_INLINE bf16x8 ld_frag(const __bf16* p) {
    union { uint4 u; bf16x8 v; } t;
    t.u = *(const uint4*)p;
    return t.v;
}
DEV_INLINE void st4_relu(__bf16* p, floatx4 a) {
    union { __bf16 h[4]; uint2 u; } t;
#pragma unroll
    for (int i = 0; i < 4; ++i) t.h[i] = (__bf16)fmaxf(a[i], 0.0f);
    *(uint2*)p = t.u;
}

// ---------------------------------------------------------------------------
// Prep: transpose + zero-pad + cvt all weight matrices into bf16 A-operand
// layout wt[n_out][k_pad] (k contiguous, 16B rows). Runs every call.
// ---------------------------------------------------------------------------
template<int N, int Kp, int Ks>
DEV_INLINE void tp(__bf16* dst, const float* __restrict__ src, int idx0, int stride) {
    for (int e = idx0; e < N * Kp; e += stride) {
        int n = e / Kp, k = e - n * Kp;
        dst[e] = (k < Ks) ? (__bf16)src[k * N + n] : (__bf16)0.0f;
    }
}

__global__ __launch_bounds__(256)
void prep_kernel(const float* __restrict__ rw1, const float* __restrict__ rw2,
                 const float* __restrict__ rw3,
                 const float* __restrict__ tw1, const float* __restrict__ tw2,
                 const float* __restrict__ tw3,
                 const float* __restrict__ mw1, const float* __restrict__ mw2,
                 const float* __restrict__ mw3, __bf16* __restrict__ wb)
{
    int i0 = blockIdx.x * 256 + threadIdx.x;
    int st = gridDim.x * 256;
    tp< 64,  32,   6>(wb + 0,     rw1, i0, st);
    tp< 64,  64,  64>(wb + 2048,  rw2, i0, st);
    tp< 32,  64,  64>(wb + 6144,  rw3, i0, st);
    tp< 64,  32,   7>(wb + 8192,  tw1, i0, st);
    tp< 64,  64,  64>(wb + 10240, tw2, i0, st);
    tp< 32,  64,  64>(wb + 14336, tw3, i0, st);
    tp<128, 128, 108>(wb + 16384, mw1, i0, st);
    tp<128, 128, 128>(wb + 32768, mw2, i0, st);
    tp< 64, 128, 128>(wb + 49152, mw3, i0, st);
}

// ---------------------------------------------------------------------------
// MFMA set encoder: [B,S,DIN] -> 64 -> 64 -> 32 -> pool (mean+max)/2 -> bf16.
// Weights are the A operand (from global, prepped layout); activations are
// the B operand in row-major [row][feat] LDS (stride 72 bf16). D reg-groups
// span 4 consecutive feats of one row -> packed ds_write_b64.
// Block = 256 thr (4 waves), 128 rows; h1/h2 wave-private (no mid barriers).
// ---------------------------------------------------------------------------
template<int DIN, int S>
__global__ __launch_bounds__(256)
void enc_mfma(const float* __restrict__ X,
              const __bf16* __restrict__ wt1, const float* __restrict__ b1,
              const __bf16* __restrict__ wt2, const float* __restrict__ b2,
              const __bf16* __restrict__ wt3, const float* __restrict__ b3,
              __bf16* __restrict__ out)
{
    constexpr int NB = 128 / S;              // batches per block (1 or 2)
    __shared__ __align__(16) __bf16 h1[128 * 72];
    __shared__ __align__(16) __bf16 h2[128 * 72];
    __shared__ float pool[512];
    float* e3 = (float*)h1;                  // [128][36] f32, aliases h1

    const int tid = threadIdx.x;
    const int w   = tid >> 6;                // wave owns rows 32w..32w+31
    const int l64 = tid & 63;
    const int ln  = l64 & 15;
    const int qd  = l64 >> 4;

    // ---- L1: K=32 (zero-padded from DIN), B-frag = x rows ----
    bf16x8 xb[2];
#pragma unroll
    for (int t = 0; t < 2; ++t) {
        int row = (2 * w + t) * 16 + ln;
        const float* xp = X + ((size_t)blockIdx.x * 128 + row) * DIN;
        bf16x8 v;
#pragma unroll
        for (int j = 0; j < 8; ++j) v[j] = (__bf16)0.0f;
        if (qd == 0) {
#pragma unroll
            for (int j = 0; j < DIN; ++j) v[j] = (__bf16)xp[j];
        }
        xb[t] = v;
    }
#pragma unroll
    for (int mt = 0; mt < 4; ++mt) {
        bf16x8 af = ld_frag(&wt1[(mt * 16 + ln) * 32 + qd * 8]);
        float4 bv = *(const float4*)&b1[mt * 16 + qd * 4];
#pragma unroll
        for (int t = 0; t < 2; ++t) {
            floatx4 acc = (floatx4){bv.x, bv.y, bv.z, bv.w};
            acc = __builtin_amdgcn_mfma_f32_16x16x32_bf16(af, xb[t], acc, 0, 0, 0);
            st4_relu(&h1[((2 * w + t) * 16 + ln) * 72 + mt * 16 + qd * 4], acc);
        }
    }

    // ---- L2: 64 -> 64 ----
    {
        bf16x8 bfr[2][2];
#pragma unroll
        for (int t = 0; t < 2; ++t)
#pragma unroll
            for (int kq = 0; kq < 2; ++kq)
                bfr[t][kq] = ld_frag(&h1[((2 * w + t) * 16 + ln) * 72 + kq * 32 + qd * 8]);
#pragma unroll
        for (int mt = 0; mt < 4; ++mt) {
            bf16x8 a0 = ld_frag(&wt2[(mt * 16 + ln) * 64 + qd * 8]);
            bf16x8 a1 = ld_frag(&wt2[(mt * 16 + ln) * 64 + 32 + qd * 8]);
            float4 bv = *(const float4*)&b2[mt * 16 + qd * 4];
#pragma unroll
            for (int t = 0; t < 2; ++t) {
                floatx4 acc = (floatx4){bv.x, bv.y, bv.z, bv.w};
                acc = __builtin_amdgcn_mfma_f32_16x16x32_bf16(a0, bfr[t][0], acc, 0, 0, 0);
                acc = __builtin_amdgcn_mfma_f32_16x16x32_bf16(a1, bfr[t][1], acc, 0, 0, 0);
                st4_relu(&h2[((2 * w + t) * 16 + ln) * 72 + mt * 16 + qd * 4], acc);
            }
        }
    }

    // ---- L3: 64 -> 32, fp32 out into e3 (aliases h1; wave-private) ----
    {
        bf16x8 bfr[2][2];
#pragma unroll
        for (int t = 0; t < 2; ++t)
#pragma unroll
            for (int kq = 0; kq < 2; ++kq)
                bfr[t][kq] = ld_frag(&h2[((2 * w + t) * 16 + ln) * 72 + kq * 32 + qd * 8]);
#pragma unroll
        for (int mt = 0; mt < 2; ++mt) {
            bf16x8 a0 = ld_frag(&wt3[(mt * 16 + ln) * 64 + qd * 8]);
            bf16x8 a1 = ld_frag(&wt3[(mt * 16 + ln) * 64 + 32 + qd * 8]);
            float4 bv = *(const float4*)&b3[mt * 16 + qd * 4];
#pragma unroll
            for (int t = 0; t < 2; ++t) {
                floatx4 acc = (floatx4){bv.x, bv.y, bv.z, bv.w};
                acc = __builtin_amdgcn_mfma_f32_16x16x32_bf16(a0, bfr[t][0], acc, 0, 0, 0);
                acc = __builtin_amdgcn_mfma_f32_16x16x32_bf16(a1, bfr[t][1], acc, 0, 0, 0);
                float4 o = {acc[0], acc[1], acc[2], acc[3]};
                *(float4*)&e3[((2 * w + t) * 16 + ln) * 36 + mt * 16 + qd * 4] = o;
            }
        }
    }
    __syncthreads();                          // e3 now read cross-wave

    // ---- pool (mean+max)/2 over S rows per batch ----
    {
        const int o  = tid & 31;
        const int bi = (tid >> 5) % NB;
        const int ch = tid / (32 * NB);
        float s = 0.0f, m = -3.4e38f;
#pragma unroll
        for (int r = 0; r < 16; ++r) {
            float v = e3[(bi * S + ch * 16 + r) * 36 + o];
            s += v;
            m = fmaxf(m, v);
        }
        pool[tid] = s;
        pool[256 + tid] = m;
    }
    __syncthreads();
    if (tid < NB * 32) {
        constexpr int C = 8 / NB;
        float s = 0.0f, m = -3.4e38f;
#pragma unroll
        for (int c = 0; c < C; ++c) {
            s += pool[tid + c * 32 * NB];
            m = fmaxf(m, pool[256 + tid + c * 32 * NB]);
        }
        size_t b = (size_t)blockIdx.x * NB + (tid >> 5);
        out[b * 32 + (tid & 31)] = (__bf16)(0.5f * (s * (1.0f / S) + m));
    }
}

// ---------------------------------------------------------------------------
// Head: concat[108 pad 128] -> 128 -> 128 -> 64 (MFMA bf16) -> 1 (fp32 dot).
// Block = 256 thr, 64 rows. Waves split the m (output-feature) dimension.
// ---------------------------------------------------------------------------
__global__ __launch_bounds__(256)
void head_mfma(const float* __restrict__ t0,
               const __bf16* __restrict__ remb, const __bf16* __restrict__ temb,
               const __bf16* __restrict__ hw1, const float* __restrict__ b1,
               const __bf16* __restrict__ hw2, const float* __restrict__ b2,
               const __bf16* __restrict__ hw3, const float* __restrict__ b3,
               const float* __restrict__ w4, const float* __restrict__ b4,
               float* __restrict__ out)
{
    __shared__ __align__(16) __bf16 cbuf[64 * 136];   // c / h2
    __shared__ __align__(16) __bf16 hbuf[64 * 136];   // h1
    __shared__ __align__(16) __bf16 h3buf[64 * 72];
    __shared__ float pbuf[256];

    const int tid = threadIdx.x;
    const int w   = tid >> 6;
    const int l64 = tid & 63;
    const int ln  = l64 & 15;
    const int qd  = l64 >> 4;
    const int g0  = blockIdx.x * 64;

    // stage c[108] = [tier0(44) | remb(32) | temb(32)] + zero pad to 128
    for (int i = tid; i < 64 * 44; i += 256) {
        int r = i / 44, k = i - r * 44;
        cbuf[r * 136 + k] = (__bf16)t0[(size_t)(g0 + r) * 44 + k];
    }
    for (int i = tid; i < 64 * 32; i += 256) {
        int r = i >> 5, k = i & 31;
        cbuf[r * 136 + 44 + k] = remb[(size_t)(g0 + r) * 32 + k];
        cbuf[r * 136 + 76 + k] = temb[(size_t)(g0 + r) * 32 + k];
    }
    for (int i = tid; i < 64 * 20; i += 256) {
        int r = i / 20, k = i - r * 20;
        cbuf[r * 136 + 108 + k] = (__bf16)0.0f;
    }
    __syncthreads();

    // L1: 128-pad -> 128, wave w owns m-tiles {2w, 2w+1}
    {
        bf16x8 bfr[4][4];
#pragma unroll
        for (int nt = 0; nt < 4; ++nt)
#pragma unroll
            for (int kq = 0; kq < 4; ++kq)
                bfr[nt][kq] = ld_frag(&cbuf[(nt * 16 + ln) * 136 + kq * 32 + qd * 8]);
#pragma unroll
        for (int m2 = 0; m2 < 2; ++m2) {
            int mt = 2 * w + m2;
            bf16x8 af[4];
#pragma unroll
            for (int kq = 0; kq < 4; ++kq)
                af[kq] = ld_frag(&hw1[(mt * 16 + ln) * 128 + kq * 32 + qd * 8]);
            float4 bv = *(const float4*)&b1[mt * 16 + qd * 4];
#pragma unroll
            for (int nt = 0; nt < 4; ++nt) {
                floatx4 acc = (floatx4){bv.x, bv.y, bv.z, bv.w};
#pragma unroll
                for (int kq = 0; kq < 4; ++kq)
                    acc = __builtin_amdgcn_mfma_f32_16x16x32_bf16(af[kq], bfr[nt][kq], acc, 0, 0, 0);
                st4_relu(&hbuf[(nt * 16 + ln) * 136 + mt * 16 + qd * 4], acc);
            }
        }
    }
    __syncthreads();

    // L2: 128 -> 128 (hbuf -> cbuf)
    {
        bf16x8 bfr[4][4];
#pragma unroll
        for (int nt = 0; nt < 4; ++nt)
#pragma unroll
            for (int kq = 0; kq < 4; ++kq)
                bfr[nt][kq] = ld_frag(&hbuf[(nt * 16 + ln) * 136 + kq * 32 + qd * 8]);
        __syncthreads();                    // all cbuf reads (L1) done before overwrite
#pragma unroll
        for (int m2 = 0; m2 < 2; ++m2) {
            int mt = 2 * w + m2;
            bf16x8 af[4];
#pragma unroll
            for (int kq = 0; kq < 4; ++kq)
                af[kq] = ld_frag(&hw2[(mt * 16 + ln) * 128 + kq * 32 + qd * 8]);
            float4 bv = *(const float4*)&b2[mt * 16 + qd * 4];
#pragma unroll
            for (int nt = 0; nt < 4; ++nt) {
                floatx4 acc = (floatx4){bv.x, bv.y, bv.z, bv.w};
#pragma unroll
                for (int kq = 0; kq < 4; ++kq)
                    acc = __builtin_amdgcn_mfma_f32_16x16x32_bf16(af[kq], bfr[nt][kq], acc, 0, 0, 0);
                st4_relu(&cbuf[(nt * 16 + ln) * 136 + mt * 16 + qd * 4], acc);
            }
        }
    }
    __syncthreads();

    // L3: 128 -> 64, wave w owns m-tile w
    {
        bf16x8 af[4];
#pragma unroll
        for (int kq = 0; kq < 4; ++kq)
            af[kq] = ld_frag(&hw3[(w * 16 + ln) * 128 + kq * 32 + qd * 8]);
        float4 bv = *(const float4*)&b3[w * 16 + qd * 4];
#pragma unroll
        for (int nt = 0; nt < 4; ++nt) {
            floatx4 acc = (floatx4){bv.x, bv.y, bv.z, bv.w};
#pragma unroll
            for (int kq = 0; kq < 4; ++kq) {
                bf16x8 bfr = ld_frag(&cbuf[(nt * 16 + ln) * 136 + kq * 32 + qd * 8]);
                acc = __builtin_amdgcn_mfma_f32_16x16x32_bf16(af[kq], bfr, acc, 0, 0, 0);
            }
            st4_relu(&h3buf[(nt * 16 + ln) * 72 + w * 16 + qd * 4], acc);
        }
    }
    __syncthreads();

    // L4: 64 -> 1, fp32; wave w handles k-slice [16w, 16w+16)
    {
        const int r = tid & 63;
        float part = 0.0f;
#pragma unroll
        for (int c = 0; c < 2; ++c) {
            bf16x8 hv = ld_frag(&h3buf[r * 72 + w * 16 + c * 8]);
#pragma unroll
            for (int u = 0; u < 8; ++u)
                part = fmaf((float)hv[u], w4[w * 16 + c * 8 + u], part);
        }
        pbuf[w * 64 + r] = part;
    }
    __syncthreads();
    if (tid < 64)
        out[g0 + tid] = pbuf[tid] + pbuf[64 + tid] + pbuf[128 + tid] +
                        pbuf[192 + tid] + b4[0];
}

extern "C" void kernel_launch(void* const* d_in, const int* in_sizes, int n_in,
                              void* d_out, int out_size, void* d_ws, size_t ws_size,
                              hipStream_t stream)
{
    const float* t0  = (const float*)d_in[0];
    const float* rX  = (const float*)d_in[1];
    const float* tX  = (const float*)d_in[2];
    const float* rw1 = (const float*)d_in[3];  const float* rb1 = (const float*)d_in[4];
    const float* rw2 = (const float*)d_in[5];  const float* rb2 = (const float*)d_in[6];
    const float* rw3 = (const float*)d_in[7];  const float* rb3 = (const float*)d_in[8];
    const float* tw1 = (const float*)d_in[9];  const float* tb1 = (const float*)d_in[10];
    const float* tw2 = (const float*)d_in[11]; const float* tb2 = (const float*)d_in[12];
    const float* tw3 = (const float*)d_in[13]; const float* tb3 = (const float*)d_in[14];
    const float* mw1 = (const float*)d_in[15]; const float* mb1 = (const float*)d_in[16];
    const float* mw2 = (const float*)d_in[17]; const float* mb2 = (const float*)d_in[18];
    const float* mw3 = (const float*)d_in[19]; const float* mb3 = (const float*)d_in[20];
    const float* mw4 = (const float*)d_in[21]; const float* mb4 = (const float*)d_in[22];
    float* out = (float*)d_out;

    const int B = 16384;
    // ws: [0,1MB) remb bf16, [1MB,2MB) temb bf16, [2MB, +112KB) prepped weights
    __bf16* remb = (__bf16*)d_ws;
    __bf16* temb = (__bf16*)((char*)d_ws + ((size_t)1 << 20));
    __bf16* wb   = (__bf16*)((char*)d_ws + ((size_t)2 << 20));
    const __bf16* rw1b = wb + 0;     const __bf16* rw2b = wb + 2048;
    const __bf16* rw3b = wb + 6144;
    const __bf16* tw1b = wb + 8192;  const __bf16* tw2b = wb + 10240;
    const __bf16* tw3b = wb + 14336;
    const __bf16* mw1b = wb + 16384; const __bf16* mw2b = wb + 32768;
    const __bf16* mw3b = wb + 49152;

    prep_kernel<<<64, 256, 0, stream>>>(rw1, rw2, rw3, tw1, tw2, tw3,
                                        mw1, mw2, mw3, wb);
    enc_mfma<6, 64> <<<(B * 64) / 128, 256, 0, stream>>>(
        rX, rw1b, rb1, rw2b, rb2, rw3b, rb3, remb);
    enc_mfma<7, 128><<<(B * 128) / 128, 256, 0, stream>>>(
        tX, tw1b, tb1, tw2b, tb2, tw3b, tb3, temb);
    head_mfma<<<B / 64, 256, 0, stream>>>(t0, remb, temb,
                                          mw1b, mb1, mw2b, mb2, mw3b, mb3,
                                          mw4, mb4, out);
}